// Round 6
// baseline (3412.825 us; speedup 1.0000x reference)
//
#include <hip/hip_runtime.h>
#include <hip/hip_cooperative_groups.h>
#include <cstdint>
#include <cstddef>

namespace cg = cooperative_groups;

#define NLV 12
#define NPL 10000
#define KE 3
#define EPL (NPL * KE)   // 30000
#define NE (11 * EPL)    // 330000
#define NT (NLV * NPL)   // 120000
#define H 100
#define H2 50
#define FD 4
#define DM 30
#define AP 52            // global pre50 row stride (13 float4)
#define SMS 56           // smA/smP row stride (14 float4; [52..55] = xs)
#define K4 56            // W4i K rows: 50 real + 2 zero-pad + 4 x-weights
#define TN 40            // nodes per block (250 blocks exactly)
#define HSS 104
#define NWS 108

__device__ __forceinline__ float sigmoidf_(float x) {
    return 1.0f / (1.0f + __expf(-x));
}
__device__ __forceinline__ float tanhf_(float x) {
    float e = __expf(2.0f * x);
    return 1.0f - 2.0f / (e + 1.0f);
}

// ---------------------------------------------------------------------------
// Weight folding per direction (PER = 2500+50+22400+400+5400 = 30750):
//  WaT[c*52+k] = (w2@pw1)[k][c] ;  b2p[c] = (b2@pw1)[c]
//  W4i[k*400+c], c=4o+g, k<50:  g0: pw2[k][o]; g1..3: sum_m pw2[k][m]*wh[(g-1)*100+o][m]
//               k=50,51: 0 ;  k=52..55 (j=k-52): g1: wi[o*4+j]; g2: wi[(100+o)*4+j]; else 0
//  b4i[c]: g0: pb2[o]; g1: bh[o]+fold+bi[o]; g2: bh[100+o]+fold+bi[100+o]; g3: bh[200+o]+fold
//  nwT[c*108+k] = (k<100) ? w1pre[k*50+c] : 0
// ---------------------------------------------------------------------------
__global__ void fold_kernel(
    const float* __restrict__ w2F, const float* __restrict__ b2F_,
    const float* __restrict__ pw1F, const float* __restrict__ pw2F,
    const float* __restrict__ pb2F, const float* __restrict__ whF,
    const float* __restrict__ bhF, const float* __restrict__ biF,
    const float* __restrict__ wiF, const float* __restrict__ w1pF,
    const float* __restrict__ w2B, const float* __restrict__ b2B_,
    const float* __restrict__ pw1B, const float* __restrict__ pw2B,
    const float* __restrict__ pb2B, const float* __restrict__ whB,
    const float* __restrict__ bhB, const float* __restrict__ biB,
    const float* __restrict__ wiB, const float* __restrict__ w1pB,
    float* __restrict__ WaTF, float* __restrict__ b2pF,
    float* __restrict__ W4iF, float* __restrict__ b4iF, float* __restrict__ nwTF,
    float* __restrict__ WaTB, float* __restrict__ b2pB,
    float* __restrict__ W4iB, float* __restrict__ b4iB, float* __restrict__ nwTB)
{
    const int PER = 30750;
    int gid = blockIdx.x * blockDim.x + threadIdx.x;
    if (gid >= 2 * PER) return;
    int dir = gid / PER;
    int i = gid - dir * PER;
    const float* w2  = dir ? w2B  : w2F;
    const float* b2  = dir ? b2B_ : b2F_;
    const float* pw1 = dir ? pw1B : pw1F;
    const float* pw2 = dir ? pw2B : pw2F;
    const float* wh  = dir ? whB  : whF;
    const float* bh  = dir ? bhB  : bhF;
    const float* bi  = dir ? biB  : biF;
    const float* wi  = dir ? wiB  : wiF;
    const float* pb2 = dir ? pb2B : pb2F;
    const float* w1p = dir ? w1pB : w1pF;
    float* WaT = dir ? WaTB : WaTF;
    float* b2p = dir ? b2pB : b2pF;
    float* W4i = dir ? W4iB : W4iF;
    float* b4i = dir ? b4iB : b4iF;
    float* nwT = dir ? nwTB : nwTF;

    if (i < 2500) {
        int c = i / 50, k = i - c * 50;
        float s = 0.f;
        for (int m = 0; m < 100; ++m) s += w2[k * 100 + m] * pw1[m * 50 + c];
        WaT[c * AP + k] = s;
    } else if (i < 2550) {
        int c = i - 2500;
        float s = 0.f;
        for (int m = 0; m < 100; ++m) s += b2[m] * pw1[m * 50 + c];
        b2p[c] = s;
    } else if (i < 24950) {
        int j = i - 2550;
        int k = j / 400, c = j - k * 400;
        int o = c >> 2, g = c & 3;
        float s = 0.f;
        if (k < 50) {
            if (g == 0) {
                s = pw2[k * 100 + o];
            } else {
                int row = (g - 1) * 100 + o;
                for (int m = 0; m < 100; ++m) s += pw2[k * 100 + m] * wh[row * 100 + m];
            }
        } else if (k >= 52) {
            int j4 = k - 52;
            if (g == 1) s = wi[o * 4 + j4];
            else if (g == 2) s = wi[(100 + o) * 4 + j4];
        }
        W4i[k * 400 + c] = s;
    } else if (i < 25350) {
        int c = i - 24950;
        int o = c >> 2, g = c & 3;
        float s;
        if (g == 0) {
            s = pb2[o];
        } else {
            int row = (g - 1) * 100 + o;
            s = bh[row];
            for (int m = 0; m < 100; ++m) s += pb2[m] * wh[row * 100 + m];
            if (g == 1) s += bi[o];
            else if (g == 2) s += bi[100 + o];
        }
        b4i[c] = s;
    } else {
        int j = i - 25350;
        int c = j / NWS, k = j - c * NWS;
        nwT[c * NWS + k] = (k < 100) ? w1p[k * 50 + c] : 0.f;
    }
}

// ---------------------------------------------------------------------------
// CSR build (grouped by src; LOCAL dst indices). counts = in-degree.
// ---------------------------------------------------------------------------
__global__ void csr_count(const int* __restrict__ src, int* __restrict__ counts)
{
    int e = blockIdx.x * blockDim.x + threadIdx.x;
    if (e >= NE) return;
    int f = e / EPL;
    atomicAdd(&counts[f * NPL + src[e] - f * NPL], 1);
}

__global__ void csr_scan(const int* __restrict__ counts, int* __restrict__ offs)
{
    int f = blockIdx.x;
    int t = threadIdx.x;
    const int base = f * NPL;
    const int CH = 40;
    __shared__ int part[256];
    int s = 0;
    for (int k = 0; k < CH; ++k) {
        int idx = t * CH + k;
        if (idx < NPL) s += counts[base + idx];
    }
    part[t] = s;
    __syncthreads();
    if (t == 0) {
        int run = 0;
        for (int j = 0; j < 256; ++j) { int tmp = part[j]; part[j] = run; run += tmp; }
    }
    __syncthreads();
    int run = part[t];
    for (int k = 0; k < CH; ++k) {
        int idx = t * CH + k;
        if (idx < NPL) { offs[base + idx] = run; run += counts[base + idx]; }
    }
}

__global__ void csr_fill(const int* __restrict__ src, const int* __restrict__ dst,
                         const int* __restrict__ offs, int* __restrict__ cursor,
                         int* __restrict__ nbrb)
{
    int e = blockIdx.x * blockDim.x + threadIdx.x;
    if (e >= NE) return;
    int f = e / EPL;
    int sl = src[e] - f * NPL;
    int p = atomicAdd(&cursor[f * NPL + sl], 1);
    nbrb[f * EPL + offs[f * NPL + sl] + p] = dst[e] - (f + 1) * NPL;
}

__global__ void pre_init(const float* __restrict__ b1,
                         float* __restrict__ pre0, float* __restrict__ pre1)
{
    int t = blockIdx.x * blockDim.x + threadIdx.x;
    if (t >= NPL * AP) return;
    int c = t % AP;
    pre0[t] = (c < H2) ? fmaxf(b1[c], 0.f) : 0.f;
    if (c >= H2) pre1[t] = 0.f;
}

// ---------------------------------------------------------------------------
// Cooperative mega-kernel: all 44 level steps + proj + cls + gate sweep.
// 250 blocks x 512 threads, 1 block/CU (97 KB LDS), grid.sync() between
// serially-dependent stages.
// ---------------------------------------------------------------------------
struct MegaP {
    const float* x;
    const float* fpre_b1; const float* bpre_b1;
    const float* fpost_b1; const float* bpost_b1;
    const float* gruf_wi; const float* gruf_bi;
    const float* grub_wi; const float* grub_bi;
    const float* proj_w; const float* proj_b;
    const float* cls_w1; const float* cls_b1;
    const float* cls_w2; const float* cls_b2;
    const int* src;
    const int* offs; const int* counts; const int* nbrb;
    float* state; float* xr; float* pred;
    float* pre0; float* pre1;
    const float* WaTF; const float* b2pF; const float* W4iF; const float* b4iF; const float* nwTF;
    const float* WaTB; const float* b2pB; const float* W4iB; const float* b4iB; const float* nwTB;
    float* out;
};

__global__ __launch_bounds__(512) void mega_kernel(MegaP p)
{
    cg::grid_group grid = cg::this_grid();
    __shared__ float smA[TN * SMS];        //  9.0 KB
    __shared__ float smP[TN * SMS];        //  9.0 KB
    __shared__ float sWaT[2][H2 * AP];     // 20.8 KB
    __shared__ float sNwT[2][H2 * NWS];    // 43.2 KB
    __shared__ float hs[TN * HSS];         // 16.6 KB
    __shared__ int sed[TN * KE];
    __shared__ int soff[TN];
    __shared__ int sdeg[TN];

    const int tid = threadIdx.x;
    const int bid = blockIdx.x;
    const int nb = bid * TN;
    const int c = tid, g = c & 3, o = c >> 2;

    // persistent LDS weights, both directions (fold_kernel ordered before us)
    for (int idx = tid; idx < H2 * AP / 4; idx += 512) {
        ((float4*)sWaT[0])[idx] = ((const float4*)p.WaTF)[idx];
        ((float4*)sWaT[1])[idx] = ((const float4*)p.WaTB)[idx];
    }
    for (int idx = tid; idx < H2 * NWS / 4; idx += 512) {
        ((float4*)sNwT[0])[idx] = ((const float4*)p.nwTF)[idx];
        ((float4*)sNwT[1])[idx] = ((const float4*)p.nwTB)[idx];
    }

    float Wc[K4];
    float b4c = 0.f, binn = 0.f, wn0 = 0.f, wn1 = 0.f, wn2 = 0.f, wn3 = 0.f;
    int curdir = -1;
    int pb = 0;
    float* preBuf[2] = { p.pre0, p.pre1 };

    for (int r = 0; r < 2; ++r) {
        const float* xrG;
        if (r == 0) {
            xrG = p.x;
        } else {
            // proj: xr = state @ proj_w + proj_b ; 1920 elems per block
            for (int k = tid; k < 1920; k += 512) {
                int t = bid * 1920 + k;
                int node = t >> 2, f = t & 3;
                const float4* rp = (const float4*)(p.state + (size_t)node * H);
                float acc = p.proj_b[f];
                for (int i4 = 0; i4 < 25; ++i4) {
                    float4 v = rp[i4];
                    acc = fmaf(v.x, p.proj_w[(4 * i4 + 0) * 4 + f], acc);
                    acc = fmaf(v.y, p.proj_w[(4 * i4 + 1) * 4 + f], acc);
                    acc = fmaf(v.z, p.proj_w[(4 * i4 + 2) * 4 + f], acc);
                    acc = fmaf(v.w, p.proj_w[(4 * i4 + 3) * 4 + f], acc);
                }
                p.xr[t] = acc;
            }
            grid.sync();
            xrG = p.xr;
        }

        for (int s = 0; s < 22; ++s) {
            int dir = (s < 11) ? 0 : 1;
            int lvl;
            const int* fedge = nullptr;
            int srcbase = 0;
            const int *boffs = nullptr, *bdeg = nullptr, *bnbr = nullptr;
            if (dir == 0) {
                int l = s + 1; lvl = l;
                fedge = p.src + (size_t)(l - 1) * EPL; srcbase = (l - 1) * NPL;
            } else {
                int f = 21 - s; lvl = f;
                boffs = p.offs + f * NPL; bdeg = p.counts + f * NPL;
                bnbr = p.nbrb + (size_t)f * EPL;
            }
            int nsel = (dir == 0) ? ((s == 10) ? 1 : 0) : ((s == 21) ? 0 : 1);
            const float* nb1 = nsel ? p.bpre_b1 : p.fpre_b1;
            const float* b2p = dir ? p.b2pB : p.b2pF;
            const float* pb1 = dir ? p.bpost_b1 : p.fpost_b1;
            const float* preIn = preBuf[pb];
            float* preOut = preBuf[pb ^ 1];
            pb ^= 1;
            float* state_out = p.state + (size_t)lvl * NPL * H;
            const float* xrL = xrG + (size_t)lvl * NPL * FD;

            if (dir != curdir) {   // reload per-direction register weights (4x/call)
                curdir = dir;
                const float* W4i = dir ? p.W4iB : p.W4iF;
                const float* b4i = dir ? p.b4iB : p.b4iF;
                const float* wi  = dir ? p.grub_wi : p.gruf_wi;
                const float* bi  = dir ? p.grub_bi : p.gruf_bi;
                if (c < 400) {
#pragma unroll
                    for (int k = 0; k < K4; ++k) Wc[k] = W4i[k * 400 + c];
                    b4c = b4i[c];
                    binn = bi[200 + o];
                    wn0 = wi[(200 + o) * 4 + 0]; wn1 = wi[(200 + o) * 4 + 1];
                    wn2 = wi[(200 + o) * 4 + 2]; wn3 = wi[(200 + o) * 4 + 3];
                }
            }

            // ---- stage edge metadata ----
            if (fedge) {
                if (tid < TN * KE) sed[tid] = fedge[nb * KE + tid] - srcbase;
            } else {
                if (tid < TN) { soff[tid] = boffs[nb + tid]; sdeg[tid] = bdeg[nb + tid]; }
            }
            __syncthreads();

            // ---- A: gather + sum pre50 rows -> smA ----
            const float4* pre4 = (const float4*)preIn;
            for (int idx = tid; idx < TN * 13; idx += 512) {
                int n = idx / 13, q = idx - n * 13;
                float4 a = make_float4(0.f, 0.f, 0.f, 0.f);
                if (fedge) {
#pragma unroll
                    for (int e = 0; e < KE; ++e) {
                        int rr = sed[KE * n + e];
                        float4 v = pre4[rr * 13 + q];
                        a.x += v.x; a.y += v.y; a.z += v.z; a.w += v.w;
                    }
                } else {
                    int off = soff[n], d = sdeg[n];
                    for (int e = 0; e < d; ++e) {
                        int rr = bnbr[off + e];
                        float4 v = pre4[rr * 13 + q];
                        a.x += v.x; a.y += v.y; a.z += v.z; a.w += v.w;
                    }
                }
                *(float4*)&smA[n * SMS + 4 * q] = a;
            }
            __syncthreads();

            // ---- B: p50 -> smP ; append xs to smP[.][52..55] ----
            const float* wa = sWaT[dir];
            for (int idx = tid; idx < TN * H2; idx += 512) {
                int n = idx / H2, cc = idx - n * H2;
                float dgv = fedge ? 3.0f : (float)sdeg[n];
                float acc = pb1[cc] + dgv * b2p[cc];
                const float4* ar = (const float4*)&smA[n * SMS];
                const float4* wr = (const float4*)&wa[cc * AP];
#pragma unroll
                for (int q = 0; q < 13; ++q) {
                    float4 av = ar[q], wv = wr[q];
                    acc = fmaf(av.x, wv.x, acc); acc = fmaf(av.y, wv.y, acc);
                    acc = fmaf(av.z, wv.z, acc); acc = fmaf(av.w, wv.w, acc);
                }
                smP[n * SMS + cc] = fmaxf(acc, 0.f);
            }
            if (tid < TN) {
                float4 xv = ((const float4*)xrL)[nb + tid];
                smP[tid * SMS + 50] = 0.f; smP[tid * SMS + 51] = 0.f;
                *(float4*)&smP[tid * SMS + 52] = xv;
            }
            __syncthreads();

            // ---- C + GRU via cross-lane shuffles ----
            if (c < 400) {
                for (int n = 0; n < TN; ++n) {
                    const float4* row = (const float4*)&smP[n * SMS];
                    float acc = b4c;
                    float4 xq = make_float4(0.f, 0.f, 0.f, 0.f);
#pragma unroll
                    for (int q = 0; q < 14; ++q) {
                        float4 pv = row[q];
                        if (q == 13) xq = pv;
                        acc = fmaf(pv.x, Wc[4 * q + 0], acc);
                        acc = fmaf(pv.y, Wc[4 * q + 1], acc);
                        acc = fmaf(pv.z, Wc[4 * q + 2], acc);
                        acc = fmaf(pv.w, Wc[4 * q + 3], acc);
                    }
                    // lanes 4o..4o+3: g0=m, g1=rpre, g2=zpre, g3=hnpre
                    float t1 = __shfl_xor(acc, 2);   // g3<-rpre, g2<-m
                    float tt = 0.f;
                    if (g == 3) {
                        float inn = binn;
                        inn = fmaf(xq.x, wn0, inn); inn = fmaf(xq.y, wn1, inn);
                        inn = fmaf(xq.z, wn2, inn); inn = fmaf(xq.w, wn3, inn);
                        float rr = sigmoidf_(t1);
                        tt = tanhf_(inn + rr * acc);
                    }
                    float t2 = __shfl_xor((g == 3) ? tt : acc, 1);  // g2<-t
                    if (g == 2) {
                        float z = sigmoidf_(acc);
                        hs[n * HSS + o] = fmaf(z, t1 - t2, t2);   // (1-z)t + z*m
                    }
                }
            }
            __syncthreads();

            // ---- D: next step's pre50 ----
            const float* nw = sNwT[nsel];
            for (int idx = tid; idx < TN * H2; idx += 512) {
                int n = idx / H2, cc = idx - n * H2;
                float acc = nb1[cc];
                const float4* hr = (const float4*)&hs[n * HSS];
                const float4* wr = (const float4*)&nw[cc * NWS];
#pragma unroll
                for (int q = 0; q < 25; ++q) {
                    float4 hv = hr[q], wv = wr[q];
                    acc = fmaf(hv.x, wv.x, acc); acc = fmaf(hv.y, wv.y, acc);
                    acc = fmaf(hv.z, wv.z, acc); acc = fmaf(hv.w, wv.w, acc);
                }
                preOut[(size_t)(nb + n) * AP + cc] = fmaxf(acc, 0.f);
            }
            // ---- E: coalesced state write ----
            for (int idx = tid; idx < TN * H; idx += 512) {
                int n = idx / H, cc = idx - n * H;
                state_out[(size_t)(nb + n) * H + cc] = hs[n * HSS + cc];
            }
            grid.sync();
        }
    }

    // ---- cls on level-0 nodes (reuse smA as [n][j] staging, stride 32) ----
    for (int idx = tid; idx < TN * DM; idx += 512) {
        int n = idx / DM, j = idx - n * DM;
        float acc = p.cls_b1[j];
        const float* sp = p.state + (size_t)(nb + n) * H;
        for (int i = 0; i < H; ++i) acc = fmaf(sp[i], p.cls_w1[i * DM + j], acc);
        smA[n * 32 + j] = acc;
    }
    __syncthreads();
    if (tid < TN) {
        float v = p.cls_b2[0];
#pragma unroll
        for (int j = 0; j < DM; ++j) v = fmaf(fmaxf(smA[tid * 32 + j], 0.f), p.cls_w2[j], v);
        p.pred[nb + tid] = sigmoidf_(v);
    }
    grid.sync();

    // ---- gate sweep ----
    for (int l = 1; l < NLV; ++l) {
        if (tid < TN) {
            int j = nb + tid;
            int e0 = (l - 1) * EPL + KE * j;
            int dg = l * NPL + j;
            float v0 = p.pred[p.src[e0 + 0]];
            float v1 = p.pred[p.src[e0 + 1]];
            float v2 = p.pred[p.src[e0 + 2]];
            const float invT = 100.0f;
            float mx = fmaxf(v0, fmaxf(v1, v2));
            float e0x = __expf((v0 - mx) * invT);
            float e1x = __expf((v1 - mx) * invT);
            float e2x = __expf((v2 - mx) * invT);
            float smax = (e0x * v0 + e1x * v1 + e2x * v2) / (e0x + e1x + e2x);
            float mn = fminf(v0, fminf(v1, v2));
            float f0 = __expf((mn - v0) * invT);
            float f1 = __expf((mn - v1) * invT);
            float f2 = __expf((mn - v2) * invT);
            float smin = (f0 * v0 + f1 * v1 + f2 * v2) / (f0 + f1 + f2);
            float am = p.x[(size_t)dg * FD + 1];
            float om = p.x[(size_t)dg * FD + 2];
            float nm = p.x[(size_t)dg * FD + 3];
            p.pred[dg] = am * smin + om * smax + nm * (3.f - (v0 + v1 + v2));
        }
        grid.sync();
    }
    if (tid < TN) p.out[nb + tid] = p.pred[(NLV - 1) * NPL + nb + tid];
}

// ---------------------------------------------------------------------------
extern "C" void kernel_launch(void* const* d_in, const int* in_sizes, int n_in,
                              void* d_out, int out_size, void* d_ws, size_t ws_size,
                              hipStream_t stream)
{
    const float* x        = (const float*)d_in[0];
    const float* fpre_w1  = (const float*)d_in[1];
    const float* fpre_b1  = (const float*)d_in[2];
    const float* fpre_w2  = (const float*)d_in[3];
    const float* fpre_b2  = (const float*)d_in[4];
    const float* fpost_w1 = (const float*)d_in[5];
    const float* fpost_b1 = (const float*)d_in[6];
    const float* fpost_w2 = (const float*)d_in[7];
    const float* fpost_b2 = (const float*)d_in[8];
    const float* bpre_w1  = (const float*)d_in[9];
    const float* bpre_b1  = (const float*)d_in[10];
    const float* bpre_w2  = (const float*)d_in[11];
    const float* bpre_b2  = (const float*)d_in[12];
    const float* bpost_w1 = (const float*)d_in[13];
    const float* bpost_b1 = (const float*)d_in[14];
    const float* bpost_w2 = (const float*)d_in[15];
    const float* bpost_b2 = (const float*)d_in[16];
    const float* gruf_wi  = (const float*)d_in[17];
    const float* gruf_wh  = (const float*)d_in[18];
    const float* gruf_bi  = (const float*)d_in[19];
    const float* gruf_bh  = (const float*)d_in[20];
    const float* grub_wi  = (const float*)d_in[21];
    const float* grub_wh  = (const float*)d_in[22];
    const float* grub_bi  = (const float*)d_in[23];
    const float* grub_bh  = (const float*)d_in[24];
    const float* proj_w   = (const float*)d_in[25];
    const float* proj_b   = (const float*)d_in[26];
    const float* cls_w1   = (const float*)d_in[27];
    const float* cls_b1   = (const float*)d_in[28];
    const float* cls_w2   = (const float*)d_in[29];
    const float* cls_b2   = (const float*)d_in[30];
    const int*   src      = (const int*)d_in[31];
    const int*   dst      = (const int*)d_in[32];
    float* out = (float*)d_out;

    size_t off = 0;
    auto carve = [&](size_t nbytes) -> void* {
        void* ptr = (char*)d_ws + off;
        off += (nbytes + 255) & ~(size_t)255;
        return ptr;
    };
    float* state = (float*)carve((size_t)NT * H * 4);
    float* xr    = (float*)carve((size_t)NT * FD * 4);
    float* pred  = (float*)carve((size_t)NT * 4);
    float* pre0  = (float*)carve((size_t)NPL * AP * 4);
    float* pre1  = (float*)carve((size_t)NPL * AP * 4);
    int*   counts= (int*)carve((size_t)11 * NPL * 4);
    int*   cursor= (int*)carve((size_t)11 * NPL * 4);
    int*   offs  = (int*)carve((size_t)11 * NPL * 4);
    int*   nbrb  = (int*)carve((size_t)NE * 4);
    float* WaTF  = (float*)carve(H2 * AP * 4);
    float* b2pF  = (float*)carve(64 * 4);
    float* W4iF  = (float*)carve(K4 * 400 * 4);
    float* b4iF  = (float*)carve(400 * 4);
    float* nwTF  = (float*)carve(H2 * NWS * 4);
    float* WaTB  = (float*)carve(H2 * AP * 4);
    float* b2pB  = (float*)carve(64 * 4);
    float* W4iB  = (float*)carve(K4 * 400 * 4);
    float* b4iB  = (float*)carve(400 * 4);
    float* nwTB  = (float*)carve(H2 * NWS * 4);

    // zero counts AND cursor including alignment padding between them
    hipMemsetAsync(counts, 0, (size_t)((char*)offs - (char*)counts), stream);

    fold_kernel<<<(2 * 30750 + 255) / 256, 256, 0, stream>>>(
        fpre_w2, fpre_b2, fpost_w1, fpost_w2, fpost_b2, gruf_wh, gruf_bh, gruf_bi, gruf_wi, fpre_w1,
        bpre_w2, bpre_b2, bpost_w1, bpost_w2, bpost_b2, grub_wh, grub_bh, grub_bi, grub_wi, bpre_w1,
        WaTF, b2pF, W4iF, b4iF, nwTF,
        WaTB, b2pB, W4iB, b4iB, nwTB);
    csr_count<<<(NE + 255) / 256, 256, 0, stream>>>(src, counts);
    csr_scan<<<11, 256, 0, stream>>>(counts, offs);
    csr_fill<<<(NE + 255) / 256, 256, 0, stream>>>(src, dst, offs, cursor, nbrb);
    pre_init<<<(NPL * AP + 255) / 256, 256, 0, stream>>>(fpre_b1, pre0, pre1);

    MegaP mp;
    mp.x = x;
    mp.fpre_b1 = fpre_b1; mp.bpre_b1 = bpre_b1;
    mp.fpost_b1 = fpost_b1; mp.bpost_b1 = bpost_b1;
    mp.gruf_wi = gruf_wi; mp.gruf_bi = gruf_bi;
    mp.grub_wi = grub_wi; mp.grub_bi = grub_bi;
    mp.proj_w = proj_w; mp.proj_b = proj_b;
    mp.cls_w1 = cls_w1; mp.cls_b1 = cls_b1;
    mp.cls_w2 = cls_w2; mp.cls_b2 = cls_b2;
    mp.src = src;
    mp.offs = offs; mp.counts = counts; mp.nbrb = nbrb;
    mp.state = state; mp.xr = xr; mp.pred = pred;
    mp.pre0 = pre0; mp.pre1 = pre1;
    mp.WaTF = WaTF; mp.b2pF = b2pF; mp.W4iF = W4iF; mp.b4iF = b4iF; mp.nwTF = nwTF;
    mp.WaTB = WaTB; mp.b2pB = b2pB; mp.W4iB = W4iB; mp.b4iB = b4iB; mp.nwTB = nwTB;
    mp.out = out;

    void* kargs[] = { &mp };
    hipLaunchCooperativeKernel((void*)mega_kernel, dim3(250), dim3(512),
                               kargs, 0, stream);
}

// Round 7
// 1524.352 us; speedup vs baseline: 2.2389x; 2.2389x over previous
//
#include <hip/hip_runtime.h>
#include <cstdint>
#include <cstddef>

#define NLV 12
#define NPL 10000
#define KE 3
#define EPL (NPL * KE)   // 30000
#define NE (11 * EPL)    // 330000
#define NT (NLV * NPL)   // 120000
#define H 100
#define H2 50
#define FD 4
#define DM 30
#define AP 52            // global pre50 row stride (13 float4)
#define SMS 56           // smA/smP row stride (14 float4; [52..55] = xs)
#define K4 56            // W4i K rows: 50 real + 2 zero-pad + 4 x-weights
#define TN 20            // nodes per block (500 blocks exactly, 2 blocks/CU)
#define HSS 100          // hs row stride (distinct-n rows hit distinct quad-banks)
#define NWS 108

__device__ __forceinline__ float sigmoidf_(float x) {
    return 1.0f / (1.0f + __expf(-x));
}
__device__ __forceinline__ float tanhf_(float x) {
    float e = __expf(2.0f * x);
    return 1.0f - 2.0f / (e + 1.0f);
}

// ---------------------------------------------------------------------------
// Weight folding per direction (PER = 2500+50+22400+400+5400 = 30750):
//  WaT[c*52+k] = (w2@pw1)[k][c] ;  b2p[c] = (b2@pw1)[c]
//  W4i[k*400+c], c=4o+g, k<50:  g0: pw2[k][o]; g1..3: sum_m pw2[k][m]*wh[(g-1)*100+o][m]
//               k=50,51: 0 ;  k=52..55 (j=k-52): g1: wi[o*4+j]; g2: wi[(100+o)*4+j]; else 0
//  b4i[c]: g0: pb2[o]; g1: bh[o]+fold+bi[o]; g2: bh[100+o]+fold+bi[100+o]; g3: bh[200+o]+fold
//  nwT[c*108+k] = (k<100) ? w1pre[k*50+c] : 0
// ---------------------------------------------------------------------------
__global__ void fold_kernel(
    const float* __restrict__ w2F, const float* __restrict__ b2F_,
    const float* __restrict__ pw1F, const float* __restrict__ pw2F,
    const float* __restrict__ pb2F, const float* __restrict__ whF,
    const float* __restrict__ bhF, const float* __restrict__ biF,
    const float* __restrict__ wiF, const float* __restrict__ w1pF,
    const float* __restrict__ w2B, const float* __restrict__ b2B_,
    const float* __restrict__ pw1B, const float* __restrict__ pw2B,
    const float* __restrict__ pb2B, const float* __restrict__ whB,
    const float* __restrict__ bhB, const float* __restrict__ biB,
    const float* __restrict__ wiB, const float* __restrict__ w1pB,
    float* __restrict__ WaTF, float* __restrict__ b2pF,
    float* __restrict__ W4iF, float* __restrict__ b4iF, float* __restrict__ nwTF,
    float* __restrict__ WaTB, float* __restrict__ b2pB,
    float* __restrict__ W4iB, float* __restrict__ b4iB, float* __restrict__ nwTB)
{
    const int PER = 30750;
    int gid = blockIdx.x * blockDim.x + threadIdx.x;
    if (gid >= 2 * PER) return;
    int dir = gid / PER;
    int i = gid - dir * PER;
    const float* w2  = dir ? w2B  : w2F;
    const float* b2  = dir ? b2B_ : b2F_;
    const float* pw1 = dir ? pw1B : pw1F;
    const float* pw2 = dir ? pw2B : pw2F;
    const float* wh  = dir ? whB  : whF;
    const float* bh  = dir ? bhB  : bhF;
    const float* bi  = dir ? biB  : biF;
    const float* wi  = dir ? wiB  : wiF;
    const float* pb2 = dir ? pb2B : pb2F;
    const float* w1p = dir ? w1pB : w1pF;
    float* WaT = dir ? WaTB : WaTF;
    float* b2p = dir ? b2pB : b2pF;
    float* W4i = dir ? W4iB : W4iF;
    float* b4i = dir ? b4iB : b4iF;
    float* nwT = dir ? nwTB : nwTF;

    if (i < 2500) {
        int c = i / 50, k = i - c * 50;
        float s = 0.f;
        for (int m = 0; m < 100; ++m) s += w2[k * 100 + m] * pw1[m * 50 + c];
        WaT[c * AP + k] = s;
    } else if (i < 2550) {
        int c = i - 2500;
        float s = 0.f;
        for (int m = 0; m < 100; ++m) s += b2[m] * pw1[m * 50 + c];
        b2p[c] = s;
    } else if (i < 24950) {
        int j = i - 2550;
        int k = j / 400, c = j - k * 400;
        int o = c >> 2, g = c & 3;
        float s = 0.f;
        if (k < 50) {
            if (g == 0) {
                s = pw2[k * 100 + o];
            } else {
                int row = (g - 1) * 100 + o;
                for (int m = 0; m < 100; ++m) s += pw2[k * 100 + m] * wh[row * 100 + m];
            }
        } else if (k >= 52) {
            int j4 = k - 52;
            if (g == 1) s = wi[o * 4 + j4];
            else if (g == 2) s = wi[(100 + o) * 4 + j4];
        }
        W4i[k * 400 + c] = s;
    } else if (i < 25350) {
        int c = i - 24950;
        int o = c >> 2, g = c & 3;
        float s;
        if (g == 0) {
            s = pb2[o];
        } else {
            int row = (g - 1) * 100 + o;
            s = bh[row];
            for (int m = 0; m < 100; ++m) s += pb2[m] * wh[row * 100 + m];
            if (g == 1) s += bi[o];
            else if (g == 2) s += bi[100 + o];
        }
        b4i[c] = s;
    } else {
        int j = i - 25350;
        int c = j / NWS, k = j - c * NWS;
        nwT[c * NWS + k] = (k < 100) ? w1p[k * 50 + c] : 0.f;
    }
}

// ---------------------------------------------------------------------------
// CSR build (grouped by src; LOCAL dst indices). counts = in-degree.
// ---------------------------------------------------------------------------
__global__ void csr_count(const int* __restrict__ src, int* __restrict__ counts)
{
    int e = blockIdx.x * blockDim.x + threadIdx.x;
    if (e >= NE) return;
    int f = e / EPL;
    atomicAdd(&counts[f * NPL + src[e] - f * NPL], 1);
}

__global__ void csr_scan(const int* __restrict__ counts, int* __restrict__ offs)
{
    int f = blockIdx.x;
    int t = threadIdx.x;
    const int base = f * NPL;
    const int CH = 40;
    __shared__ int part[256];
    int s = 0;
    for (int k = 0; k < CH; ++k) {
        int idx = t * CH + k;
        if (idx < NPL) s += counts[base + idx];
    }
    part[t] = s;
    __syncthreads();
    if (t == 0) {
        int run = 0;
        for (int j = 0; j < 256; ++j) { int tmp = part[j]; part[j] = run; run += tmp; }
    }
    __syncthreads();
    int run = part[t];
    for (int k = 0; k < CH; ++k) {
        int idx = t * CH + k;
        if (idx < NPL) { offs[base + idx] = run; run += counts[base + idx]; }
    }
}

__global__ void csr_fill(const int* __restrict__ src, const int* __restrict__ dst,
                         const int* __restrict__ offs, int* __restrict__ cursor,
                         int* __restrict__ nbrb)
{
    int e = blockIdx.x * blockDim.x + threadIdx.x;
    if (e >= NE) return;
    int f = e / EPL;
    int sl = src[e] - f * NPL;
    int p = atomicAdd(&cursor[f * NPL + sl], 1);
    nbrb[f * EPL + offs[f * NPL + sl] + p] = dst[e] - (f + 1) * NPL;
}

__global__ void pre_init(const float* __restrict__ b1,
                         float* __restrict__ pre0, float* __restrict__ pre1)
{
    int t = blockIdx.x * blockDim.x + threadIdx.x;
    if (t >= NPL * AP) return;
    int c = t % AP;
    pre0[t] = (c < H2) ? fmaxf(b1[c], 0.f) : 0.f;
    if (c >= H2) pre1[t] = 0.f;
}

// ---------------------------------------------------------------------------
// Fused level step v4 (multi-launch; round-6 body, TN=20, 2 blocks/CU).
//  A: agg = gathered pre50 sums -> smA ; xs appended to smP rows
//  B: p50 = relu(agg@WaT + deg*b2p + pb1) -> smP[0..49]
//  C: 400 lanes own cols c=4o+g, 56 weights in VGPRs; K=56 GEMM with
//     broadcast LDS rows; GRU solved in-wave via shfl_xor(2),shfl_xor(1)
//  D: pre50_out = relu(nb1 + hs@nwT)  (LDS weights)
//  E: coalesced state write
// ---------------------------------------------------------------------------
__global__ __launch_bounds__(512, 4) void k4_kernel(
    const float* __restrict__ preIn, float* __restrict__ preOut,
    const int* __restrict__ fedge, int srcbase,
    const int* __restrict__ boffs, const int* __restrict__ bdeg,
    const int* __restrict__ bnbr,
    const float* __restrict__ xrL,
    const float* __restrict__ WaT, const float* __restrict__ b2p,
    const float* __restrict__ pb1,
    const float* __restrict__ W4i, const float* __restrict__ b4i,
    const float* __restrict__ wi, const float* __restrict__ bi,
    const float* __restrict__ nwT, const float* __restrict__ nb1,
    float* __restrict__ state_out)
{
    __shared__ float smA[TN * SMS];      // 4.5 KB
    __shared__ float smP[TN * SMS];      // 4.5 KB
    __shared__ float sWaT[H2 * AP];      // 10.4 KB
    __shared__ float sNwT[H2 * NWS];     // 21.6 KB
    __shared__ float hs[TN * HSS];       // 8.0 KB
    __shared__ int sed[TN * KE];
    __shared__ int soff[TN];
    __shared__ int sdeg[TN];

    const int tid = threadIdx.x;
    const int nb = blockIdx.x * TN;
    const int c = tid, g = c & 3, o = c >> 2;

    // per-thread register weights (coalesced global reads, L2-resident)
    float Wc[K4];
    float b4c = 0.f, binn = 0.f, wn0 = 0.f, wn1 = 0.f, wn2 = 0.f, wn3 = 0.f;
    if (c < 400) {
#pragma unroll
        for (int k = 0; k < K4; ++k) Wc[k] = W4i[k * 400 + c];
        b4c = b4i[c];
        binn = bi[200 + o];
        wn0 = wi[(200 + o) * 4 + 0]; wn1 = wi[(200 + o) * 4 + 1];
        wn2 = wi[(200 + o) * 4 + 2]; wn3 = wi[(200 + o) * 4 + 3];
    }
    // LDS staging (active direction only)
    for (int idx = tid; idx < H2 * AP / 4; idx += 512)
        ((float4*)sWaT)[idx] = ((const float4*)WaT)[idx];
    for (int idx = tid; idx < H2 * NWS / 4; idx += 512)
        ((float4*)sNwT)[idx] = ((const float4*)nwT)[idx];
    if (fedge) {
        if (tid < TN * KE) sed[tid] = fedge[nb * KE + tid] - srcbase;
    } else {
        if (tid < TN) { soff[tid] = boffs[nb + tid]; sdeg[tid] = bdeg[nb + tid]; }
    }
    __syncthreads();

    // ---- A: gather + sum pre50 rows -> smA ----
    const float4* pre4 = (const float4*)preIn;
    for (int idx = tid; idx < TN * 13; idx += 512) {
        int n = idx / 13, q = idx - n * 13;
        float4 a = make_float4(0.f, 0.f, 0.f, 0.f);
        if (fedge) {
#pragma unroll
            for (int e = 0; e < KE; ++e) {
                int rr = sed[KE * n + e];
                float4 v = pre4[rr * 13 + q];
                a.x += v.x; a.y += v.y; a.z += v.z; a.w += v.w;
            }
        } else {
            int off = soff[n], d = sdeg[n];
            for (int e = 0; e < d; ++e) {
                int rr = bnbr[off + e];
                float4 v = pre4[rr * 13 + q];
                a.x += v.x; a.y += v.y; a.z += v.z; a.w += v.w;
            }
        }
        *(float4*)&smA[n * SMS + 4 * q] = a;
    }
    __syncthreads();

    // ---- B: p50 -> smP ; append xs to smP[.][52..55] ----
    for (int idx = tid; idx < TN * H2; idx += 512) {
        int n = idx / H2, cc = idx - n * H2;
        float dgv = fedge ? 3.0f : (float)sdeg[n];
        float acc = pb1[cc] + dgv * b2p[cc];
        const float4* ar = (const float4*)&smA[n * SMS];
        const float4* wr = (const float4*)&sWaT[cc * AP];
#pragma unroll
        for (int q = 0; q < 13; ++q) {
            float4 av = ar[q], wv = wr[q];
            acc = fmaf(av.x, wv.x, acc); acc = fmaf(av.y, wv.y, acc);
            acc = fmaf(av.z, wv.z, acc); acc = fmaf(av.w, wv.w, acc);
        }
        smP[n * SMS + cc] = fmaxf(acc, 0.f);
    }
    if (tid < TN) {
        float4 xv = ((const float4*)xrL)[nb + tid];
        smP[tid * SMS + 50] = 0.f; smP[tid * SMS + 51] = 0.f;
        *(float4*)&smP[tid * SMS + 52] = xv;
    }
    __syncthreads();

    // ---- C + GRU via cross-lane shuffles ----
    if (c < 400) {
        for (int n = 0; n < TN; ++n) {
            const float4* row = (const float4*)&smP[n * SMS];
            float acc = b4c;
            float4 xq = make_float4(0.f, 0.f, 0.f, 0.f);
#pragma unroll
            for (int q = 0; q < 14; ++q) {
                float4 pv = row[q];
                if (q == 13) xq = pv;
                acc = fmaf(pv.x, Wc[4 * q + 0], acc);
                acc = fmaf(pv.y, Wc[4 * q + 1], acc);
                acc = fmaf(pv.z, Wc[4 * q + 2], acc);
                acc = fmaf(pv.w, Wc[4 * q + 3], acc);
            }
            // lanes 4o..4o+3: g0=m, g1=rpre, g2=zpre, g3=hnpre
            float t1 = __shfl_xor(acc, 2);   // g3<-rpre, g2<-m
            float tt = 0.f;
            if (g == 3) {
                float inn = binn;
                inn = fmaf(xq.x, wn0, inn); inn = fmaf(xq.y, wn1, inn);
                inn = fmaf(xq.z, wn2, inn); inn = fmaf(xq.w, wn3, inn);
                float rr = sigmoidf_(t1);
                tt = tanhf_(inn + rr * acc);
            }
            float t2 = __shfl_xor((g == 3) ? tt : acc, 1);  // g2<-t
            if (g == 2) {
                float z = sigmoidf_(acc);
                hs[n * HSS + o] = fmaf(z, t1 - t2, t2);   // (1-z)t + z*m
            }
        }
    }
    __syncthreads();

    // ---- D: next step's pre50 ----
    for (int idx = tid; idx < TN * H2; idx += 512) {
        int n = idx / H2, cc = idx - n * H2;
        float acc = nb1[cc];
        const float4* hr = (const float4*)&hs[n * HSS];
        const float4* wr = (const float4*)&sNwT[cc * NWS];
#pragma unroll
        for (int q = 0; q < 25; ++q) {
            float4 hv = hr[q], wv = wr[q];
            acc = fmaf(hv.x, wv.x, acc); acc = fmaf(hv.y, wv.y, acc);
            acc = fmaf(hv.z, wv.z, acc); acc = fmaf(hv.w, wv.w, acc);
        }
        preOut[(size_t)(nb + n) * AP + cc] = fmaxf(acc, 0.f);
    }
    // ---- E: coalesced state write ----
    for (int idx = tid; idx < TN * H; idx += 512) {
        int n = idx / H, cc = idx - n * H;
        state_out[(size_t)(nb + n) * H + cc] = hs[n * HSS + cc];
    }
}

// ---------------------------------------------------------------------------
// xr = state @ proj_w + proj_b ; thread = (node, f)
// ---------------------------------------------------------------------------
__global__ __launch_bounds__(256) void proj_kernel(
    const float* __restrict__ state, const float* __restrict__ pw,
    const float* __restrict__ pb, float* __restrict__ xr)
{
    int t = blockIdx.x * 256 + threadIdx.x;
    if (t >= NT * FD) return;
    int node = t >> 2, f = t & 3;
    const float4* rp = (const float4*)(state + (size_t)node * H);
    float acc = pb[f];
    for (int i4 = 0; i4 < 25; ++i4) {
        float4 v = rp[i4];
        acc = fmaf(v.x, pw[(4 * i4 + 0) * 4 + f], acc);
        acc = fmaf(v.y, pw[(4 * i4 + 1) * 4 + f], acc);
        acc = fmaf(v.z, pw[(4 * i4 + 2) * 4 + f], acc);
        acc = fmaf(v.w, pw[(4 * i4 + 3) * 4 + f], acc);
    }
    xr[t] = acc;
}

// ---------------------------------------------------------------------------
__global__ void cls_kernel(const float* __restrict__ state,
                           const float* __restrict__ w1, const float* __restrict__ b1,
                           const float* __restrict__ w2, const float* __restrict__ b2,
                           float* __restrict__ pred)
{
    int n = blockIdx.x * blockDim.x + threadIdx.x;
    if (n >= NPL) return;
    float h[DM];
#pragma unroll
    for (int j = 0; j < DM; ++j) h[j] = b1[j];
    const float* sp = state + (size_t)n * H;
    for (int i = 0; i < H; ++i) {
        float s = sp[i];
#pragma unroll
        for (int j = 0; j < DM; ++j) h[j] = fmaf(s, w1[i * DM + j], h[j]);
    }
    float v = b2[0];
#pragma unroll
    for (int j = 0; j < DM; ++j) v = fmaf(fmaxf(h[j], 0.f), w2[j], v);
    pred[n] = sigmoidf_(v);
}

// ---------------------------------------------------------------------------
__global__ void gate_kernel(const float* __restrict__ x, const int* __restrict__ src,
                            float* __restrict__ pred, int l)
{
    int j = blockIdx.x * blockDim.x + threadIdx.x;
    if (j >= NPL) return;
    int e0 = (l - 1) * EPL + KE * j;
    int dg = l * NPL + j;
    float v0 = pred[src[e0 + 0]];
    float v1 = pred[src[e0 + 1]];
    float v2 = pred[src[e0 + 2]];
    const float invT = 100.0f;
    float mx = fmaxf(v0, fmaxf(v1, v2));
    float e0x = __expf((v0 - mx) * invT);
    float e1x = __expf((v1 - mx) * invT);
    float e2x = __expf((v2 - mx) * invT);
    float smax = (e0x * v0 + e1x * v1 + e2x * v2) / (e0x + e1x + e2x);
    float mn = fminf(v0, fminf(v1, v2));
    float f0 = __expf((mn - v0) * invT);
    float f1 = __expf((mn - v1) * invT);
    float f2 = __expf((mn - v2) * invT);
    float smin = (f0 * v0 + f1 * v1 + f2 * v2) / (f0 + f1 + f2);
    float am = x[(size_t)dg * FD + 1];
    float om = x[(size_t)dg * FD + 2];
    float nm = x[(size_t)dg * FD + 3];
    pred[dg] = am * smin + om * smax + nm * (3.f - (v0 + v1 + v2));
}

__global__ void copy_kernel(const float* __restrict__ pred, float* __restrict__ out)
{
    int j = blockIdx.x * blockDim.x + threadIdx.x;
    if (j < NPL) out[j] = pred[(NLV - 1) * NPL + j];
}

// ---------------------------------------------------------------------------
extern "C" void kernel_launch(void* const* d_in, const int* in_sizes, int n_in,
                              void* d_out, int out_size, void* d_ws, size_t ws_size,
                              hipStream_t stream)
{
    const float* x        = (const float*)d_in[0];
    const float* fpre_w1  = (const float*)d_in[1];
    const float* fpre_b1  = (const float*)d_in[2];
    const float* fpre_w2  = (const float*)d_in[3];
    const float* fpre_b2  = (const float*)d_in[4];
    const float* fpost_w1 = (const float*)d_in[5];
    const float* fpost_b1 = (const float*)d_in[6];
    const float* fpost_w2 = (const float*)d_in[7];
    const float* fpost_b2 = (const float*)d_in[8];
    const float* bpre_w1  = (const float*)d_in[9];
    const float* bpre_b1  = (const float*)d_in[10];
    const float* bpre_w2  = (const float*)d_in[11];
    const float* bpre_b2  = (const float*)d_in[12];
    const float* bpost_w1 = (const float*)d_in[13];
    const float* bpost_b1 = (const float*)d_in[14];
    const float* bpost_w2 = (const float*)d_in[15];
    const float* bpost_b2 = (const float*)d_in[16];
    const float* gruf_wi  = (const float*)d_in[17];
    const float* gruf_wh  = (const float*)d_in[18];
    const float* gruf_bi  = (const float*)d_in[19];
    const float* gruf_bh  = (const float*)d_in[20];
    const float* grub_wi  = (const float*)d_in[21];
    const float* grub_wh  = (const float*)d_in[22];
    const float* grub_bi  = (const float*)d_in[23];
    const float* grub_bh  = (const float*)d_in[24];
    const float* proj_w   = (const float*)d_in[25];
    const float* proj_b   = (const float*)d_in[26];
    const float* cls_w1   = (const float*)d_in[27];
    const float* cls_b1   = (const float*)d_in[28];
    const float* cls_w2   = (const float*)d_in[29];
    const float* cls_b2   = (const float*)d_in[30];
    const int*   src      = (const int*)d_in[31];
    const int*   dst      = (const int*)d_in[32];
    float* out = (float*)d_out;

    size_t off = 0;
    auto carve = [&](size_t nbytes) -> void* {
        void* ptr = (char*)d_ws + off;
        off += (nbytes + 255) & ~(size_t)255;
        return ptr;
    };
    float* state = (float*)carve((size_t)NT * H * 4);
    float* xr    = (float*)carve((size_t)NT * FD * 4);
    float* pred  = (float*)carve((size_t)NT * 4);
    float* pre0  = (float*)carve((size_t)NPL * AP * 4);
    float* pre1  = (float*)carve((size_t)NPL * AP * 4);
    int*   counts= (int*)carve((size_t)11 * NPL * 4);
    int*   cursor= (int*)carve((size_t)11 * NPL * 4);
    int*   offs  = (int*)carve((size_t)11 * NPL * 4);
    int*   nbrb  = (int*)carve((size_t)NE * 4);
    float* WaTF  = (float*)carve(H2 * AP * 4);
    float* b2pF  = (float*)carve(64 * 4);
    float* W4iF  = (float*)carve(K4 * 400 * 4);
    float* b4iF  = (float*)carve(400 * 4);
    float* nwTF  = (float*)carve(H2 * NWS * 4);
    float* WaTB  = (float*)carve(H2 * AP * 4);
    float* b2pB  = (float*)carve(64 * 4);
    float* W4iB  = (float*)carve(K4 * 400 * 4);
    float* b4iB  = (float*)carve(400 * 4);
    float* nwTB  = (float*)carve(H2 * NWS * 4);

    // zero counts AND cursor including alignment padding between them
    hipMemsetAsync(counts, 0, (size_t)((char*)offs - (char*)counts), stream);

    fold_kernel<<<(2 * 30750 + 255) / 256, 256, 0, stream>>>(
        fpre_w2, fpre_b2, fpost_w1, fpost_w2, fpost_b2, gruf_wh, gruf_bh, gruf_bi, gruf_wi, fpre_w1,
        bpre_w2, bpre_b2, bpost_w1, bpost_w2, bpost_b2, grub_wh, grub_bh, grub_bi, grub_wi, bpre_w1,
        WaTF, b2pF, W4iF, b4iF, nwTF,
        WaTB, b2pB, W4iB, b4iB, nwTB);
    csr_count<<<(NE + 255) / 256, 256, 0, stream>>>(src, counts);
    csr_scan<<<11, 256, 0, stream>>>(counts, offs);
    csr_fill<<<(NE + 255) / 256, 256, 0, stream>>>(src, dst, offs, cursor, nbrb);
    pre_init<<<(NPL * AP + 255) / 256, 256, 0, stream>>>(fpre_b1, pre0, pre1);

    float* preBuf[2] = { pre0, pre1 };
    int pb = 0;
    const int k4Grid = NPL / TN;   // 500

    for (int r = 0; r < 2; ++r) {
        const float* xr_use;
        if (r == 0) {
            xr_use = x;
        } else {
            proj_kernel<<<(NT * FD + 255) / 256, 256, 0, stream>>>(state, proj_w, proj_b, xr);
            xr_use = xr;
        }
        // forward levels 1..11
        for (int l = 1; l < NLV; ++l) {
            bool lastf = (l == NLV - 1);
            k4_kernel<<<k4Grid, 512, 0, stream>>>(
                preBuf[pb], preBuf[pb ^ 1],
                src + (size_t)(l - 1) * EPL, (l - 1) * NPL,
                nullptr, nullptr, nullptr,
                xr_use + (size_t)l * NPL * FD,
                WaTF, b2pF, fpost_b1, W4iF, b4iF, gruf_wi, gruf_bi,
                lastf ? nwTB : nwTF, lastf ? bpre_b1 : fpre_b1,
                state + (size_t)l * NPL * H);
            pb ^= 1;
        }
        // backward levels 10..0
        for (int f = NLV - 2; f >= 0; --f) {
            bool lastb = (f == 0);
            k4_kernel<<<k4Grid, 512, 0, stream>>>(
                preBuf[pb], preBuf[pb ^ 1],
                nullptr, 0,
                offs + (size_t)f * NPL, counts + (size_t)f * NPL, nbrb + (size_t)f * EPL,
                xr_use + (size_t)f * NPL * FD,
                WaTB, b2pB, bpost_b1, W4iB, b4iB, grub_wi, grub_bi,
                lastb ? nwTF : nwTB, lastb ? fpre_b1 : bpre_b1,
                state + (size_t)f * NPL * H);
            pb ^= 1;
        }
    }

    cls_kernel<<<(NPL + 255) / 256, 256, 0, stream>>>(state, cls_w1, cls_b1, cls_w2, cls_b2, pred);
    for (int l = 1; l < NLV; ++l)
        gate_kernel<<<(NPL + 255) / 256, 256, 0, stream>>>(x, src, pred, l);
    copy_kernel<<<(NPL + 255) / 256, 256, 0, stream>>>(pred, out);
}